// Round 1
// baseline (1972.528 us; speedup 1.0000x reference)
//
#include <hip/hip_runtime.h>
#include <hip/hip_bf16.h>
#include <math.h>

// Problem constants (LSTMEmbed): B=64 graphs, T=2048 tokens, N=512 nodes,
// D=128 latent, V=vocab (from in_sizes), 4D=512 gates.
#define B_  64
#define T_  2048
#define N_  512
#define D_  128
#define G4  512   // 4*D

__device__ __forceinline__ float sigmoid_f(float x) {
    return 1.f / (1.f + __expf(-x));
}
__device__ __forceinline__ float tanh_f(float x) {
    // stable: exp of negative only
    float e = __expf(-2.f * fabsf(x));
    float t = (1.f - e) / (1.f + e);
    return x < 0.f ? -t : t;
}

// K1: proj[v][g] = sum_d w2v[v][d] * W_ih[g][d] + b_ih[g] + b_hh[g]
// 8 vocab rows per block, 512 threads (one gate column each).
__global__ __launch_bounds__(512) void proj_kernel(
    const float* __restrict__ w2v, const float* __restrict__ W_ih,
    const float* __restrict__ b_ih, const float* __restrict__ b_hh,
    float* __restrict__ proj, int V) {
    const int n  = threadIdx.x;       // gate column 0..511
    const int v0 = blockIdx.x * 8;
    __shared__ float emb_s[8 * 128];

    if (n < 256) {                    // 8 rows x 32 float4 = 256 float4
        int r = n >> 5;
        if (v0 + r < V) {
            ((float4*)emb_s)[n] = ((const float4*)(w2v + (size_t)v0 * 128))[n];
        }
    }

    float4 wr[32];
    {
        const float4* wsrc = (const float4*)(W_ih + (size_t)n * 128);
#pragma unroll
        for (int i = 0; i < 32; ++i) wr[i] = wsrc[i];
    }
    float bias = b_ih[n] + b_hh[n];
    __syncthreads();

#pragma unroll
    for (int r = 0; r < 8; ++r) {
        if (v0 + r < V) {
            const float4* e4 = (const float4*)(emb_s + r * 128);
            float acc = bias;
#pragma unroll
            for (int kk = 0; kk < 32; ++kk) {
                float4 e = e4[kk];
                acc = fmaf(wr[kk].x, e.x, acc);
                acc = fmaf(wr[kk].y, e.y, acc);
                acc = fmaf(wr[kk].z, e.z, acc);
                acc = fmaf(wr[kk].w, e.w, acc);
            }
            proj[(size_t)(v0 + r) * G4 + n] = acc;
        }
    }
}

// K2a: head[b*T + t] = -1
__global__ void init_head_kernel(int* __restrict__ head, int n) {
    int i = blockIdx.x * blockDim.x + threadIdx.x;
    if (i < n) head[i] = -1;
}

// K2b: per-(b,t) linked list of node slots k with node_pos[b,k] == t
__global__ void build_list_kernel(const int* __restrict__ node_pos,
                                  int* __restrict__ head, int* __restrict__ nxt,
                                  int n) {
    int i = blockIdx.x * blockDim.x + threadIdx.x;
    if (i < n) {
        int b = i / N_;
        int k = i - b * N_;
        int t = node_pos[i];
        int old = atomicExch(&head[b * T_ + t], k);
        nxt[i] = old;
    }
}

// K3: sequential LSTM per graph. 64 blocks x 512 threads.
// Thread t owns gate row t: W_hh row in 128 VGPRs; h broadcast via LDS.
__global__ __launch_bounds__(512, 2) void lstm_kernel(
    const int* __restrict__ token_idx, const float* __restrict__ proj,
    const float* __restrict__ W_hh, const int* __restrict__ head,
    const int* __restrict__ nxt, float* __restrict__ out) {
    const int b = blockIdx.x;
    const int t = threadIdx.x;        // gate index 0..511
    __shared__ float4 hbuf4[32];      // h(t-1), 128 floats
    __shared__ float  gbuf[512];      // activated gates
    float* hbuf = (float*)hbuf4;

    float4 w4[32];
    {
        const float4* wsrc = (const float4*)(W_hh + (size_t)t * 128);
#pragma unroll
        for (int i = 0; i < 32; ++i) w4[i] = wsrc[i];
    }

    const int* tokrow = token_idx + b * T_;
    int tok_nxt = tokrow[1];
    float xg = proj[(size_t)tokrow[0] * G4 + t];
    float h_reg = 0.f, cx = 0.f;
    if (t < 128) hbuf[t] = 0.f;
    const int gate = t >> 7;          // 0:i 1:f 2:g 3:o
    __syncthreads();

    for (int step = 0; step < T_; ++step) {
        // prefetch next step's input-gate vector (L2/L3-resident table)
        float xg_n = proj[(size_t)tok_nxt * G4 + t];
        int tok_n2 = tokrow[step + 2 < T_ ? step + 2 : T_ - 1];

        // gates[t] = xg[t] + sum_k W_hh[t][k] * h[k]
        float acc = xg;
#pragma unroll
        for (int kk = 0; kk < 32; ++kk) {
            float4 h4 = hbuf4[kk];    // broadcast read, conflict-free
            acc = fmaf(w4[kk].x, h4.x, acc);
            acc = fmaf(w4[kk].y, h4.y, acc);
            acc = fmaf(w4[kk].z, h4.z, acc);
            acc = fmaf(w4[kk].w, h4.w, acc);
        }
        float a = (gate == 2) ? tanh_f(acc) : sigmoid_f(acc);
        gbuf[t] = a;
        __syncthreads();

        if (t < 128) {
            float ig = gbuf[t];
            float fg = gbuf[t + 128];
            float gg = gbuf[t + 256];
            float og = gbuf[t + 384];
            cx = fmaf(fg, cx, ig * gg);
            h_reg = og * tanh_f(cx);
            hbuf[t] = h_reg;
        }
        __syncthreads();

        if (t < 128) {
            // scatter h to every node slot with node_pos == step
            int k = head[b * T_ + step];
            while (k >= 0) {
                out[((size_t)b * (N_ + 1) + k) * D_ + t] = h_reg;
                k = nxt[b * N_ + k];
            }
        }
        xg = xg_n;
        tok_nxt = tok_n2;
    }
    if (t < 128) {
        out[((size_t)b * (N_ + 1) + N_) * D_ + t] = h_reg;  // final hT
    }
}

extern "C" void kernel_launch(void* const* d_in, const int* in_sizes, int n_in,
                              void* d_out, int out_size, void* d_ws, size_t ws_size,
                              hipStream_t stream) {
    const int*   token_idx = (const int*)d_in[0];
    const int*   node_pos  = (const int*)d_in[1];
    const float* w2v       = (const float*)d_in[2];
    const float* W_ih      = (const float*)d_in[3];
    const float* W_hh      = (const float*)d_in[4];
    const float* b_ih      = (const float*)d_in[5];
    const float* b_hh      = (const float*)d_in[6];
    float* out = (float*)d_out;

    const int V = in_sizes[2] / D_;   // vocab size (5000)

    // workspace layout: proj [V*512 f32] | head [B*T i32] | nxt [B*N i32]
    char* ws = (char*)d_ws;
    size_t proj_bytes = (size_t)V * G4 * sizeof(float);
    proj_bytes = (proj_bytes + 15) & ~(size_t)15;
    float* proj = (float*)ws;
    int*   head = (int*)(ws + proj_bytes);
    int*   nxt  = (int*)(ws + proj_bytes + ((size_t)B_ * T_ * 4));

    proj_kernel<<<(V + 7) / 8, 512, 0, stream>>>(w2v, W_ih, b_ih, b_hh, proj, V);
    init_head_kernel<<<(B_ * T_ + 255) / 256, 256, 0, stream>>>(head, B_ * T_);
    build_list_kernel<<<(B_ * N_ + 255) / 256, 256, 0, stream>>>(node_pos, head, nxt, B_ * N_);
    lstm_kernel<<<B_, 512, 0, stream>>>(token_idx, proj, W_hh, head, nxt, out);
}

// Round 2
// 1682.628 us; speedup vs baseline: 1.1723x; 1.1723x over previous
//
#include <hip/hip_runtime.h>
#include <hip/hip_bf16.h>
#include <math.h>

// LSTMEmbed: B=64 graphs, T=2048 tokens, N=512 nodes, D=128 latent, 4D=512 gates.
#define B_  64
#define T_  2048
#define N_  512
#define D_  128
#define G4  512   // 4*D

typedef _Float16 half8 __attribute__((ext_vector_type(8)));
typedef float    f32x4 __attribute__((ext_vector_type(4)));

__device__ __forceinline__ float sigmoid_f(float x) {
    return 1.f / (1.f + __expf(-x));
}
__device__ __forceinline__ float tanh_f(float x) {
    float e = __expf(-2.f * fabsf(x));
    float t = (1.f - e) / (1.f + e);
    return x < 0.f ? -t : t;
}

// K1: proj[v][g] = sum_d w2v[v][d] * W_ih[g][d] + b_ih[g] + b_hh[g]
__global__ __launch_bounds__(512) void proj_kernel(
    const float* __restrict__ w2v, const float* __restrict__ W_ih,
    const float* __restrict__ b_ih, const float* __restrict__ b_hh,
    float* __restrict__ proj, int V) {
    const int n  = threadIdx.x;
    const int v0 = blockIdx.x * 8;
    __shared__ float emb_s[8 * 128];

    if (n < 256) {
        int r = n >> 5;
        if (v0 + r < V) {
            ((float4*)emb_s)[n] = ((const float4*)(w2v + (size_t)v0 * 128))[n];
        }
    }
    float4 wr[32];
    {
        const float4* wsrc = (const float4*)(W_ih + (size_t)n * 128);
#pragma unroll
        for (int i = 0; i < 32; ++i) wr[i] = wsrc[i];
    }
    float bias = b_ih[n] + b_hh[n];
    __syncthreads();

#pragma unroll
    for (int r = 0; r < 8; ++r) {
        if (v0 + r < V) {
            const float4* e4 = (const float4*)(emb_s + r * 128);
            float acc = bias;
#pragma unroll
            for (int kk = 0; kk < 32; ++kk) {
                float4 e = e4[kk];
                acc = fmaf(wr[kk].x, e.x, acc);
                acc = fmaf(wr[kk].y, e.y, acc);
                acc = fmaf(wr[kk].z, e.z, acc);
                acc = fmaf(wr[kk].w, e.w, acc);
            }
            proj[(size_t)(v0 + r) * G4 + n] = acc;
        }
    }
}

__global__ void init_head_kernel(int* __restrict__ head, int n) {
    int i = blockIdx.x * blockDim.x + threadIdx.x;
    if (i < n) head[i] = -1;
}

__global__ void build_list_kernel(const int* __restrict__ node_pos,
                                  int* __restrict__ head, int* __restrict__ nxt,
                                  int n) {
    int i = blockIdx.x * blockDim.x + threadIdx.x;
    if (i < n) {
        int b = i / N_;
        int k = i - b * N_;
        int t = node_pos[i];
        int old = atomicExch(&head[b * T_ + t], k);
        nxt[i] = old;
    }
}

// K_prep: convert W_hh (f32 [512][128]) into MFMA A-fragment-ordered f16.
// Fragment: A[row = l&15][k = (l>>4)*8 + j] for m-tile mt, k-tile kt.
// Layout: Whf[(((mt*4 + kt)*4 + lhi)*16 + r)*8 + j] = f16(W_hh[mt*16+r][kt*32+lhi*8+j])
__global__ void prep_whh_kernel(const float* __restrict__ W_hh,
                                _Float16* __restrict__ Whf) {
    int g = blockIdx.x * blockDim.x + threadIdx.x;   // 0..8191 (groups of 8)
    if (g >= 512 * 128 / 8) return;
    int r   = g & 15;
    int lhi = (g >> 4) & 3;
    int kt  = (g >> 6) & 3;
    int mt  = g >> 8;            // 0..31
    int m = mt * 16 + r;
    int kb = kt * 32 + lhi * 8;
    const float* src = W_hh + (size_t)m * 128 + kb;
#pragma unroll
    for (int j = 0; j < 8; ++j) {
        Whf[(size_t)g * 8 + j] = (_Float16)src[j];
    }
}

// K3: MFMA LSTM. 64 blocks x 512 threads (8 waves).
// Wave w owns m-tiles {w, w+8, w+16, w+24} (gate rows w*16.. etc).
// h kept as one 128-f16 row in LDS; B-frag reads broadcast it to all 16 cols,
// so every C column holds the full gate vector (col-independent acc init from
// proj makes this exact). Lanes l&15==0 publish raw gates; threads 0..127 do
// activations + cell update + output scatter.
__global__ __launch_bounds__(512, 2) void lstm_mfma_kernel(
    const int* __restrict__ token_idx, const float* __restrict__ proj,
    const _Float16* __restrict__ Whf, const int* __restrict__ head,
    const int* __restrict__ nxt, float* __restrict__ out) {
    const int b   = blockIdx.x;
    const int tid = threadIdx.x;
    const int w   = tid >> 6;        // wave 0..7
    const int l   = tid & 63;
    const int lhi = l >> 4;          // 0..3
    const int l15 = l & 15;

    __shared__ __align__(16) _Float16 h_lds[128];
    __shared__ __align__(16) float    gbuf[512];

    // Load A fragments: 4 m-tiles x 4 k-tiles, 8 f16 each (64 VGPRs).
    half8 afrag[4][4];
#pragma unroll
    for (int mi = 0; mi < 4; ++mi) {
        int mt = w + 8 * mi;
#pragma unroll
        for (int kt = 0; kt < 4; ++kt) {
            afrag[mi][kt] = *(const half8*)&Whf[((size_t)((mt * 4 + kt) * 4 + lhi) * 16 + l15) * 8];
        }
    }

    if (tid < 128) h_lds[tid] = (_Float16)0.f;

    const int* tokrow = token_idx + b * T_;
    float cx = 0.f, h_reg = 0.f;

    // xg for step 0; tokA = token for step 1 (prefetched one iter ahead).
    int tok0 = tokrow[0];
    int tokA = tokrow[1];
    f32x4 xg[4];
#pragma unroll
    for (int mi = 0; mi < 4; ++mi) {
        xg[mi] = *(const f32x4*)&proj[(size_t)tok0 * G4 + (w + 8 * mi) * 16 + lhi * 4];
    }
    __syncthreads();

    for (int step = 0; step < T_; ++step) {
        // Prefetch token two ahead and next step's xg (consumed next iter).
        int tokB = tokrow[step + 2 < T_ ? step + 2 : T_ - 1];
        f32x4 xg_n[4];
#pragma unroll
        for (int mi = 0; mi < 4; ++mi) {
            xg_n[mi] = *(const f32x4*)&proj[(size_t)tokA * G4 + (w + 8 * mi) * 16 + lhi * 4];
        }

        // B fragments: h broadcast (addr independent of l&15).
        half8 bfrag[4];
#pragma unroll
        for (int kt = 0; kt < 4; ++kt) {
            bfrag[kt] = *(const half8*)&h_lds[kt * 32 + lhi * 8];
        }

        // gates = xg + W_hh @ h
        f32x4 acc[4];
#pragma unroll
        for (int mi = 0; mi < 4; ++mi) {
            acc[mi] = xg[mi];
#pragma unroll
            for (int kt = 0; kt < 4; ++kt) {
                acc[mi] = __builtin_amdgcn_mfma_f32_16x16x32_f16(
                    afrag[mi][kt], bfrag[kt], acc[mi], 0, 0, 0);
            }
        }

        // Publish raw gates (C row = lhi*4+reg, col-independent).
        if (l15 == 0) {
#pragma unroll
            for (int mi = 0; mi < 4; ++mi) {
                *(f32x4*)&gbuf[(w + 8 * mi) * 16 + lhi * 4] = acc[mi];
            }
        }
        __syncthreads();

        if (tid < 128) {
            float gi = sigmoid_f(gbuf[tid]);
            float gf = sigmoid_f(gbuf[tid + 128]);
            float gg = tanh_f(gbuf[tid + 256]);
            float go = sigmoid_f(gbuf[tid + 384]);
            cx = fmaf(gf, cx, gi * gg);
            h_reg = go * tanh_f(cx);
            h_lds[tid] = (_Float16)h_reg;
            // scatter h to node slots with node_pos == step
            int k = head[b * T_ + step];
            while (k >= 0) {
                out[((size_t)b * (N_ + 1) + k) * D_ + tid] = h_reg;
                k = nxt[b * N_ + k];
            }
        }
#pragma unroll
        for (int mi = 0; mi < 4; ++mi) xg[mi] = xg_n[mi];
        tokA = tokB;
        __syncthreads();
    }
    if (tid < 128) {
        out[((size_t)b * (N_ + 1) + N_) * D_ + tid] = h_reg;  // final hT
    }
}

extern "C" void kernel_launch(void* const* d_in, const int* in_sizes, int n_in,
                              void* d_out, int out_size, void* d_ws, size_t ws_size,
                              hipStream_t stream) {
    const int*   token_idx = (const int*)d_in[0];
    const int*   node_pos  = (const int*)d_in[1];
    const float* w2v       = (const float*)d_in[2];
    const float* W_ih      = (const float*)d_in[3];
    const float* W_hh      = (const float*)d_in[4];
    const float* b_ih      = (const float*)d_in[5];
    const float* b_hh      = (const float*)d_in[6];
    float* out = (float*)d_out;

    const int V = in_sizes[2] / D_;

    // ws: proj [V*512 f32] | head [B*T i32] | nxt [B*N i32] | Whf [512*128 f16]
    char* ws = (char*)d_ws;
    size_t proj_bytes = ((size_t)V * G4 * sizeof(float) + 15) & ~(size_t)15;
    float*     proj = (float*)ws;
    int*       head = (int*)(ws + proj_bytes);
    int*       nxt  = (int*)(ws + proj_bytes + (size_t)B_ * T_ * 4);
    _Float16*  Whf  = (_Float16*)(ws + proj_bytes + (size_t)B_ * T_ * 4 + (size_t)B_ * N_ * 4);

    proj_kernel<<<(V + 7) / 8, 512, 0, stream>>>(w2v, W_ih, b_ih, b_hh, proj, V);
    init_head_kernel<<<(B_ * T_ + 255) / 256, 256, 0, stream>>>(head, B_ * T_);
    build_list_kernel<<<(B_ * N_ + 255) / 256, 256, 0, stream>>>(node_pos, head, nxt, B_ * N_);
    prep_whh_kernel<<<(512 * 128 / 8 + 255) / 256, 256, 0, stream>>>(W_hh, Whf);
    lstm_mfma_kernel<<<B_, 512, 0, stream>>>(token_idx, proj, Whf, head, nxt, out);
}